// Round 1
// baseline (3430.776 us; speedup 1.0000x reference)
//
#include <hip/hip_runtime.h>
#include <math.h>

#define KB 8      // spline bins
#define TT 8      // transforms
#define HH 64     // hidden width
#define PHI_N 23  // 3*K - 1
#define BOUNDF 5.0f

// -log(2.5 - (-1.75)) = -log(4.25)
#define LN_P_OUT (-1.4469189829363254f)
// 0.5*log(2*pi)
#define HALF_LN_2PI 0.91893853320467274f

__device__ __forceinline__ float softplusf(float x) {
    // jax.nn.softplus = logaddexp(x, 0) = max(x,0) + log1p(exp(-|x|))
    return fmaxf(x, 0.f) + log1pf(expf(-fabsf(x)));
}

__global__ __launch_bounds__(256) void gyro_main(
    const float* __restrict__ z_in,
    const float* __restrict__ log_age,
    const float* __restrict__ bprp0,
    const float* __restrict__ log_bprp0_err,
    const float* __restrict__ mem_prob,
    const float* __restrict__ W1,   // (T,3,H)
    const float* __restrict__ b1,   // (T,H)
    const float* __restrict__ W2,   // (T,H,H)
    const float* __restrict__ b2,   // (T,H)
    const float* __restrict__ W3,   // (T,H,PHI)
    const float* __restrict__ b3,   // (T,PHI)
    double* __restrict__ partials,
    int B)
{
    const int i = blockIdx.x * blockDim.x + threadIdx.x;

    float lc = 0.f;
    if (i < B) {
        const float c0 = log_age[i];
        const float c1 = bprp0[i];
        const float c2 = log_bprp0_err[i];
        float z = z_in[i];
        float logdet = 0.f;

        #pragma unroll 1
        for (int t = 0; t < TT; ++t) {
            const float* __restrict__ w1  = W1 + t * 3 * HH;
            const float* __restrict__ bb1 = b1 + t * HH;
            const float* __restrict__ w2  = W2 + t * HH * HH;
            const float* __restrict__ bb2 = b2 + t * HH;
            const float* __restrict__ w3  = W3 + t * HH * PHI_N;
            const float* __restrict__ bb3 = b3 + t * PHI_N;

            // ---- layer 1: h1 = relu(ctx @ W1 + b1) ----
            float h1[HH];
            #pragma unroll
            for (int j = 0; j < HH; ++j) {
                float a = bb1[j];
                a += c0 * w1[0 * HH + j];
                a += c1 * w1[1 * HH + j];
                a += c2 * w1[2 * HH + j];
                h1[j] = fmaxf(a, 0.f);
            }

            // ---- layer 2 + 3 fused: phi += relu(h1@W2+b2) @ W3, blocked by 16 outputs ----
            float phi[PHI_N];
            #pragma unroll
            for (int j3 = 0; j3 < PHI_N; ++j3) phi[j3] = bb3[j3];

            #pragma unroll 1
            for (int jo = 0; jo < HH / 16; ++jo) {
                float acc[16];
                #pragma unroll
                for (int jj = 0; jj < 16; ++jj) acc[jj] = bb2[jo * 16 + jj];
                #pragma unroll
                for (int k2 = 0; k2 < HH; ++k2) {
                    const float hv = h1[k2];
                    #pragma unroll
                    for (int jj = 0; jj < 16; ++jj)
                        acc[jj] += hv * w2[k2 * HH + jo * 16 + jj];
                }
                #pragma unroll
                for (int jj = 0; jj < 16; ++jj) {
                    const float v = fmaxf(acc[jj], 0.f);
                    #pragma unroll
                    for (int j3 = 0; j3 < PHI_N; ++j3)
                        phi[j3] += v * w3[(jo * 16 + jj) * PHI_N + j3];
                }
            }

            // ---- RQS spline forward on z with phi = [widths(8) | heights(8) | derivs(7)] ----
            // softmax(widths) -> x knots
            float xk[KB + 1], yk[KB + 1], dv[KB + 1];
            {
                float mx = phi[0];
                #pragma unroll
                for (int k = 1; k < KB; ++k) mx = fmaxf(mx, phi[k]);
                float ev[KB]; float se = 0.f;
                #pragma unroll
                for (int k = 0; k < KB; ++k) { ev[k] = expf(phi[k] - mx); se += ev[k]; }
                const float inv = 1.f / se;
                xk[0] = -BOUNDF;
                float cs = 0.f;
                #pragma unroll
                for (int k = 0; k < KB; ++k) { cs += ev[k]; xk[k + 1] = BOUNDF * (2.f * cs * inv - 1.f); }
            }
            {
                float mx = phi[KB];
                #pragma unroll
                for (int k = 1; k < KB; ++k) mx = fmaxf(mx, phi[KB + k]);
                float ev[KB]; float se = 0.f;
                #pragma unroll
                for (int k = 0; k < KB; ++k) { ev[k] = expf(phi[KB + k] - mx); se += ev[k]; }
                const float inv = 1.f / se;
                yk[0] = -BOUNDF;
                float cs = 0.f;
                #pragma unroll
                for (int k = 0; k < KB; ++k) { cs += ev[k]; yk[k + 1] = BOUNDF * (2.f * cs * inv - 1.f); }
            }
            dv[0] = 1.f;
            dv[KB] = 1.f;
            #pragma unroll
            for (int k = 0; k < KB - 1; ++k) dv[k + 1] = softplusf(phi[2 * KB + k]);

            const bool inside = fabsf(z) < BOUNDF;
            const float xc = fminf(fmaxf(z, -BOUNDF), BOUNDF);

            // bin selection (unrolled cndmask chain; bin 0 default)
            float x0 = xk[0], x1 = xk[1], y0 = yk[0], y1 = yk[1], d0c = dv[0], d1c = dv[1];
            #pragma unroll
            for (int m = 1; m < KB; ++m) {
                const bool c = (xc >= xk[m]);
                x0  = c ? xk[m]     : x0;
                x1  = c ? xk[m + 1] : x1;
                y0  = c ? yk[m]     : y0;
                y1  = c ? yk[m + 1] : y1;
                d0c = c ? dv[m]     : d0c;
                d1c = c ? dv[m + 1] : d1c;
            }

            const float wk  = x1 - x0;
            const float hk  = y1 - y0;
            const float s   = hk / wk;
            const float xi  = (xc - x0) / wk;
            const float xi1 = 1.f - xi;
            const float den = s + (d1c + d0c - 2.f * s) * xi * xi1;
            const float y   = y0 + hk * (s * xi * xi + d0c * xi * xi1) / den;
            const float ld  = 2.f * logf(s)
                            + logf(d1c * xi * xi + 2.f * s * xi * xi1 + d0c * xi1 * xi1)
                            - 2.f * logf(den);

            z = inside ? y : z;
            logdet += inside ? ld : 0.f;
        }

        const float logp = -0.5f * z * z - HALF_LN_2PI + logdet;

        float pm = mem_prob[i];
        pm = (pm != pm) ? 0.9f : pm;       // NaN -> P_MEM_DEFAULT
        const float nfw = pm * 0.95f;      // p_mem * (1 - P_OUTLIER)

        const float a = logf(nfw) + logp;
        const float b = logf(1.f - nfw) + LN_P_OUT;
        const float mx2 = fmaxf(a, b);
        const float mn2 = fminf(a, b);
        // logaddexp; handles -inf via exp(-inf)=0
        lc = mx2 + log1pf(expf(mn2 - mx2));
    }

    // ---- deterministic block reduction (double) ----
    double acc = (double)lc;
    #pragma unroll
    for (int off = 32; off > 0; off >>= 1) acc += __shfl_down(acc, off, 64);

    __shared__ double sm[4];
    const int lane = threadIdx.x & 63;
    const int wid  = threadIdx.x >> 6;
    if (lane == 0) sm[wid] = acc;
    __syncthreads();
    if (threadIdx.x == 0) {
        partials[blockIdx.x] = sm[0] + sm[1] + sm[2] + sm[3];
    }
}

__global__ __launch_bounds__(256) void gyro_reduce(
    const double* __restrict__ partials, int n, float* __restrict__ out, int B)
{
    double s = 0.0;
    for (int i = threadIdx.x; i < n; i += 256) s += partials[i];
    #pragma unroll
    for (int off = 32; off > 0; off >>= 1) s += __shfl_down(s, off, 64);

    __shared__ double sm[4];
    const int lane = threadIdx.x & 63;
    const int wid  = threadIdx.x >> 6;
    if (lane == 0) sm[wid] = s;
    __syncthreads();
    if (threadIdx.x == 0) {
        const double tot = sm[0] + sm[1] + sm[2] + sm[3];
        out[0] = (float)(-tot / (double)B);
    }
}

extern "C" void kernel_launch(void* const* d_in, const int* in_sizes, int n_in,
                              void* d_out, int out_size, void* d_ws, size_t ws_size,
                              hipStream_t stream) {
    const float* z_in   = (const float*)d_in[0];
    const float* lage   = (const float*)d_in[1];
    const float* bprp   = (const float*)d_in[2];
    const float* lberr  = (const float*)d_in[3];
    const float* memp   = (const float*)d_in[4];
    const float* W1     = (const float*)d_in[5];
    const float* b1     = (const float*)d_in[6];
    const float* W2     = (const float*)d_in[7];
    const float* b2     = (const float*)d_in[8];
    const float* W3     = (const float*)d_in[9];
    const float* b3     = (const float*)d_in[10];

    const int B = in_sizes[1];                 // log_age is (B,)
    const int nblocks = (B + 255) / 256;

    double* partials = (double*)d_ws;

    gyro_main<<<nblocks, 256, 0, stream>>>(z_in, lage, bprp, lberr, memp,
                                           W1, b1, W2, b2, W3, b3,
                                           partials, B);
    gyro_reduce<<<1, 256, 0, stream>>>(partials, nblocks, (float*)d_out, B);
}